// Round 6
// baseline (1715.267 us; speedup 1.0000x reference)
//
#include <hip/hip_runtime.h>
#include <cstdint>

// Problem constants
#define BB 2
#define TT 5
#define CC 64
#define HH 128
#define WW 128
#define GG 8
#define KKD 9
#define OFFC 144
#define H2 64
#define W2 64
#define TCF 2
#define HW (HH*WW)
#define HW2 (H2*W2)
#define PLANE1 278784  // 132*132*16 shorts (full-res padded NHWC chunk plane)
#define PLANE0 69696   // 66*66*16 shorts (half-res padded NHWC chunk plane)

typedef __attribute__((ext_vector_type(4))) short short4v;
typedef __attribute__((ext_vector_type(8))) short short8;
typedef __attribute__((ext_vector_type(4))) float floatx4;
typedef __attribute__((ext_vector_type(16))) float floatx16;

static __device__ __forceinline__ unsigned short f2bf(float f) {
    unsigned int u = __float_as_uint(f);
    unsigned int r = (u + 0x7fffu + ((u >> 16) & 1u)) >> 16;
    return (unsigned short)r;
}

typedef __attribute__((address_space(1))) const unsigned int g_u32;
typedef __attribute__((address_space(3))) unsigned int l_u32;
static __device__ __forceinline__ void async16(const short* g, short* l) {
    __builtin_amdgcn_global_load_lds((g_u32*)g, (l_u32*)l, 16, 0, 0);
}

// ------------- dconv weight swizzle into 16x16x32 MFMA A-frag order (bf16) -----------
// layout: [kc(18)][ocF(4)][lane(64)][j(8)]
// value = w[oc = ocF*16 + (lane&15)][cin = ck/9][kt = ck%9], ck = kc*32+((lane>>4)&3)*8+j
__global__ void wswzD_k(const float* __restrict__ w, short* __restrict__ ws) {
    int idx = blockIdx.x * 256 + threadIdx.x;
    if (idx >= 36864) return;
    int j = idx & 7;
    int lane = (idx >> 3) & 63;
    int ocF = (idx >> 9) & 3;
    int kc = idx >> 11;
    int ck = kc * 32 + ((lane >> 4) & 3) * 8 + j;
    int oc = ocF * 16 + (lane & 15);
    int cin = ck / 9;
    int kt = ck - cin * 9;
    ws[idx] = (short)f2bf(w[((size_t)oc * 64 + cin) * 9 + kt]);
}

// ---------------- conv weight swizzle into MFMA fragment order (bf16) ----------------
// layout: [chunk(8)][tap(TAPS)][ocF(5)][lane(64)][j(8)]
template <int TAPS>
__global__ void wswz_k(const float* __restrict__ w, short* __restrict__ ws) {
    int idx = blockIdx.x * 256 + threadIdx.x;
    if (idx >= 8 * TAPS * 5 * 512) return;
    int jj = idx & 7;
    int lane = (idx >> 3) & 63;
    int rest = idx >> 9;
    int ocF = rest % 5;
    int ct = rest / 5;
    int tap = ct % TAPS;
    int chunk = ct / TAPS;
    int oc = ocF * 32 + (lane & 31);
    int cin = chunk * 16 + (lane >> 5) * 8 + jj;
    float v = 0.f;
    if (oc < OFFC) v = w[((size_t)oc * 128 + cin) * TAPS + tap];
    ws[idx] = (short)f2bf(v);
}

// ---------------- 2x2 average pool -> padded NHWC-bf16 chunk planes ----------------
__global__ void avgpool_k(const float* __restrict__ x, short* __restrict__ x2T) {
    __shared__ float sL[64 * 17];
    const int h2 = blockIdx.x;
    const int chunk = blockIdx.y;
    const int img = blockIdx.z;
    const int tid = threadIdx.x;
    const float* base = x + ((size_t)img * 64 + chunk * 16) * HW + (size_t)(2 * h2) * WW;
#pragma unroll
    for (int it = 0; it < 4; ++it) {
        int e = it * 256 + tid;
        int cin = e >> 6, w2 = e & 63;
        const float* sp = base + (size_t)cin * HW + 2 * w2;
        sL[w2 * 17 + cin] = 0.25f * (sp[0] + sp[1] + sp[WW] + sp[WW + 1]);
    }
    __syncthreads();
    int w2 = tid >> 2, cg = tid & 3;
    short4v sv;
#pragma unroll
    for (int q = 0; q < 4; ++q) sv[q] = (short)f2bf(sL[w2 * 17 + cg * 4 + q]);
    *(short4v*)&x2T[((size_t)img * 4 + chunk) * PLANE0 +
                    ((size_t)(h2 + 1) * 66 + (w2 + 1)) * 16 + cg * 4] = sv;
}

// ---------------- center-frame transpose -> padded NHWC-bf16 chunk planes ------------
__global__ void xtrans_k(const float* __restrict__ x, short* __restrict__ xT) {
    __shared__ float sL[128 * 17];
    const int row = blockIdx.x;
    const int chunk = blockIdx.y;
    const int b = blockIdx.z;
    const int tid = threadIdx.x;
    const float* base = x + ((size_t)(b * 5 + TCF) * 64 + chunk * 16) * HW + (size_t)row * WW;
#pragma unroll
    for (int it = 0; it < 8; ++it) {
        int e = it * 256 + tid;
        int cin = e >> 7, col = e & 127;
        sL[col * 17 + cin] = base[(size_t)cin * HW + col];
    }
    __syncthreads();
    int col = tid >> 1, half = tid & 1;
    short8 sv;
#pragma unroll
    for (int q = 0; q < 8; ++q) sv[q] = (short)f2bf(sL[col * 17 + half * 8 + q]);
    *(short8*)&xT[((size_t)b * 4 + chunk) * PLANE1 +
                  ((size_t)(row + 2) * 132 + (col + 2)) * 16 + half * 8] = sv;
}

// ---------------- MFMA conv from NHWC-bf16 planes, Cout=144 (padded 160) -------------
template <int MODE>
__global__ __launch_bounds__(512) void convmf_k(
    const short* __restrict__ srcAT, const short* __restrict__ srcBT,
    const short* __restrict__ wswz, const float* __restrict__ bias,
    const float* __restrict__ addend, float* __restrict__ out) {
    constexpr int KS = MODE ? 5 : 3;
    constexpr int IM = MODE ? 128 : 64;
    constexpr int PD = IM + KS - 1;
    constexpr int TAPS = KS * KS;
    constexpr int OROWS = MODE ? 2 : 4;
    constexpr int SROWS = OROWS + KS - 1;
    constexpr int PLANE = PD * PD * 16;
    constexpr int SLAB16 = SROWS * PD * 2;

    __shared__ __align__(16) short stg[2][SROWS * PD * 16];

    const int bj = blockIdx.z;
    const int b = bj >> 2;
    const int j = bj & 3;
    const int i = j + (j >= 2 ? 1 : 0);
    const int y0 = blockIdx.x * OROWS;
    const int tid = threadIdx.x;
    const int wave = tid >> 6;
    const int lane = tid & 63;
    const int l31 = lane & 31;
    const int quad = lane >> 5;
    const int wr = MODE ? (wave >> 2) : (wave >> 1);
    const int wc0 = MODE ? ((wave & 3) * 32) : ((wave & 1) * 32);

    const short* srcA;
    const short* srcB;
    if (MODE == 0) {
        srcA = srcAT + (size_t)((b * 5 + i) * 4) * PLANE;
        srcB = srcAT + (size_t)((b * 5 + TCF) * 4) * PLANE;
    } else {
        srcA = srcAT + (size_t)(bj * 4) * PLANE;
        srcB = srcBT + (size_t)(b * 4) * PLANE;
    }

    floatx16 acc[5];
#pragma unroll
    for (int o = 0; o < 5; ++o)
#pragma unroll
        for (int g = 0; g < 16; ++g) acc[o][g] = 0.f;

    auto stage = [&](int c, int sIdx) {
        const short* plane = (c < 4) ? (srcA + (size_t)c * PLANE)
                                     : (srcB + (size_t)(c - 4) * PLANE);
        const short* srcRow = plane + (size_t)y0 * (PD * 16);
        short* dst = stg[sIdx];
        for (int base = wave * 64; base < SLAB16; base += 512) {
            int b2 = min(base, SLAB16 - 64);
            async16(srcRow + (size_t)(b2 + lane) * 8, dst + (size_t)b2 * 8);
        }
    };

    stage(0, 0);
    for (int c = 0; c < 8; ++c) {
        __syncthreads();
        if (c < 7) stage(c + 1, (c + 1) & 1);
        const short* sbuf = stg[c & 1];
        const short* wpc = wswz + (size_t)c * TAPS * 2560 + lane * 8;
#pragma unroll 5
        for (int tap = 0; tap < TAPS; ++tap) {
            const int ky = tap / KS, kx = tap - ky * KS;
            short8 wf[5];
            const short* wp = wpc + (size_t)tap * 2560;
#pragma unroll
            for (int o = 0; o < 5; ++o) wf[o] = *(const short8*)(wp + o * 512);
            short8 pf = *(const short8*)(sbuf +
                ((size_t)(wr + ky) * PD + (wc0 + kx + l31)) * 16 + quad * 8);
#pragma unroll
            for (int o = 0; o < 5; ++o)
                acc[o] = __builtin_amdgcn_mfma_f32_32x32x16_bf16(wf[o], pf, acc[o], 0, 0, 0);
        }
    }

    const size_t imgBase = (size_t)bj * OFFC * (IM * IM);
    const size_t rowAddr = imgBase + (size_t)(y0 + wr) * IM + wc0 + l31;
#pragma unroll
    for (int o = 0; o < 5; ++o) {
        const int rmax = (o == 4) ? 8 : 16;
#pragma unroll
        for (int r = 0; r < 16; ++r) {
            if (r >= rmax) break;
            int oc = o * 32 + (r & 3) + 8 * (r >> 2) + 4 * quad;
            float v = acc[o][r] + bias[oc];
            size_t a = rowAddr + (size_t)oc * (IM * IM);
            if (MODE == 1) v += addend[a];
            out[a] = v;
        }
    }
}

// ---------------- bilinear 2x upsample * 2.0 ----------------
__global__ void upsample_k(const float* __restrict__ off2, float* __restrict__ off2u) {
    int idx = blockIdx.x * 256 + threadIdx.x;  // < 18874368
    int ox = idx & 127;
    int oy = (idx >> 7) & 127;
    int p = idx >> 14;
    const float* sp = off2 + (size_t)p * HW2;
    float sy = 0.5f * oy - 0.25f;
    float sx = 0.5f * ox - 0.25f;
    float y0f = floorf(sy), x0f = floorf(sx);
    int y0 = (int)y0f, x0 = (int)x0f;
    float fy = sy - y0f, fx = sx - x0f;
    int y0c = max(y0, 0), y1c = min(y0 + 1, 63);
    int x0c = max(x0, 0), x1c = min(x0 + 1, 63);
    float v00 = sp[y0c * 64 + x0c], v01 = sp[y0c * 64 + x1c];
    float v10 = sp[y1c * 64 + x0c], v11 = sp[y1c * 64 + x1c];
    float v = v00 * (1.f - fy) * (1.f - fx) + v01 * (1.f - fy) * fx +
              v10 * fy * (1.f - fx) + v11 * fy * fx;
    off2u[idx] = 2.0f * v;
}

// ---------------- deformable conv (3x3, G=8 offset groups) ----------------
// block = 256 thr (4 waves) per 16-px row segment; 18.7 KB LDS -> 8 blocks/CU.
// Phase A: thread = (px16, g8, chHalf2), 4 channels each, scalar NCHW fp32 gathers.
// Phase B: 16x16x32 MFMA, A=weights(m=oc), B=samples(n=px); K split across wave pairs.
#define SROW16 584
__global__ __launch_bounds__(256, 8) void dconv_k(
    const float* __restrict__ x,    // (B,T,C,H,W)
    const float* __restrict__ off,  // (BJ,144,H,W)
    const short* __restrict__ wsD,  // swizzled A-frags [kc18][ocF4][lane64][8]
    float* __restrict__ out, short* __restrict__ z1T, int outMode) {
    const int bj = blockIdx.y;
    const int b = bj >> 2;
    const int j = bj & 3;
    const int i = j + (j >= 2 ? 1 : 0);
    const int seg = blockIdx.x;  // 0..1023
    const int y = seg >> 3;
    const int x0 = (seg & 7) << 4;
    const int tid = threadIdx.x;

    __shared__ short sS[16 * SROW16];  // 18688 B; aliased as float Pbuf[2][16][66] later
    float* Pbuf = (float*)sS;

    const float* xin = x + (size_t)(b * TT + i) * CC * HW;
    const float* offp = off + (size_t)bj * OFFC * HW + y * WW + x0;

    // ---- phase A: bilinear sampling into LDS ----
    {
        const int px = tid & 15;
        const int g = (tid >> 4) & 7;
        const int ch = tid >> 7;  // 0..1 (channel half)
        short* srow = sS + px * SROW16 + g * 72 + ch * 36;
        const float* offG = offp + (size_t)g * 18 * HW + px;
        const float* xbase = xin + (size_t)(g * 8 + ch * 4) * HW;
#pragma unroll
        for (int k = 0; k < 9; ++k) {
            float dy = offG[(size_t)(2 * k) * HW];
            float dx = offG[(size_t)(2 * k + 1) * HW];
            const int kyy = k / 3 - 1;
            const int kxx = k % 3 - 1;
            float sy = (float)(y + kyy) + dy;
            float sx = (float)(x0 + px + kxx) + dx;
            float y0f = floorf(sy), x0f = floorf(sx);
            int iy = (int)y0f, ix = (int)x0f;
            float wy = sy - y0f, wx = sx - x0f;
            bool yv0 = (iy >= 0) & (iy < HH);
            bool yv1 = (iy + 1 >= 0) & (iy + 1 < HH);
            bool xv0 = (ix >= 0) & (ix < WW);
            bool xv1 = (ix + 1 >= 0) & (ix + 1 < WW);
            float w00 = (yv0 && xv0) ? (1.f - wy) * (1.f - wx) : 0.f;
            float w01 = (yv0 && xv1) ? (1.f - wy) * wx : 0.f;
            float w10 = (yv1 && xv0) ? wy * (1.f - wx) : 0.f;
            float w11 = (yv1 && xv1) ? wy * wx : 0.f;
            int iy0 = min(max(iy, 0), HH - 1);
            int iy1 = min(max(iy + 1, 0), HH - 1);
            int ix0 = min(max(ix, 0), WW - 1);
            int ix1 = min(max(ix + 1, 0), WW - 1);
            int o00 = iy0 * WW + ix0, o01 = iy0 * WW + ix1;
            int o10 = iy1 * WW + ix0, o11 = iy1 * WW + ix1;
            const float* xp = xbase;
#pragma unroll
            for (int c = 0; c < 4; ++c) {
                float v = xp[o00] * w00 + xp[o01] * w01 + xp[o10] * w10 + xp[o11] * w11;
                srow[c * 9 + k] = (short)f2bf(v);
                xp += HW;
            }
        }
    }
    __syncthreads();

    // ---- phase B: C[oc 64][px 16] = W * S, K=576, MFMA 16x16x32 ----
    const int wv = tid >> 6;      // wave 0..3
    const int lane = tid & 63;
    const int h = wv & 1;         // oc half (32 oc)
    const int kh = wv >> 1;       // K half (9 kc)
    const int quad = (lane >> 4) & 3;
    floatx4 acc[2];
#pragma unroll
    for (int f = 0; f < 2; ++f)
#pragma unroll
        for (int r = 0; r < 4; ++r) acc[f][r] = 0.f;

    const short* aBase = sS + (lane & 15) * SROW16 + quad * 8;
    const short* bBase = wsD + ((size_t)(h * 2) * 64 + lane) * 8;
    for (int kc = kh * 9; kc < kh * 9 + 9; ++kc) {
        short8 sf = *(const short8*)(aBase + kc * 32);
        short8 wf0 = *(const short8*)(bBase + (size_t)(kc * 4) * 512);
        short8 wf1 = *(const short8*)(bBase + (size_t)(kc * 4 + 1) * 512);
        acc[0] = __builtin_amdgcn_mfma_f32_16x16x32_bf16(wf0, sf, acc[0], 0, 0, 0);
        acc[1] = __builtin_amdgcn_mfma_f32_16x16x32_bf16(wf1, sf, acc[1], 0, 0, 0);
    }

    __syncthreads();  // all waves done reading sS; alias as Pbuf
    {
        const int px = lane & 15;
#pragma unroll
        for (int f = 0; f < 2; ++f)
#pragma unroll
            for (int r = 0; r < 4; ++r) {
                int oc = h * 32 + f * 16 + quad * 4 + r;
                Pbuf[(kh * 16 + px) * 66 + oc] = acc[f][r];
            }
    }
    __syncthreads();

    // ---- epilogue: reduce K-halves, store ----
    if (outMode == 0) {
        // z1T padded NHWC-bf16 chunk planes: [bj][chunk(4)][132][132][16]
        const int px = tid >> 4;
        const int s = tid & 15;
        const int c = s >> 2;
        const int q = s & 3;
        short4v sv;
#pragma unroll
        for (int e = 0; e < 4; ++e) {
            int oc = c * 16 + q * 4 + e;
            float v = Pbuf[px * 66 + oc] + Pbuf[(16 + px) * 66 + oc];
            sv[e] = (short)f2bf(v);
        }
        *(short4v*)&z1T[((size_t)bj * 4 + c) * PLANE1 +
                        ((size_t)(y + 2) * 132 + (x0 + 2 + px)) * 16 + q * 4] = sv;
    } else {
        const size_t planeBase = (size_t)(b * TT + i) * CC * HW;
        const size_t rowBase = planeBase + (size_t)y * WW + x0;
        const int oc = tid >> 2;
        const int pq = tid & 3;
        float4 fv;
        float* fp = (float*)&fv;
#pragma unroll
        for (int e = 0; e < 4; ++e) {
            int px = pq * 4 + e;
            fp[e] = Pbuf[px * 66 + oc] + Pbuf[(16 + px) * 66 + oc];
        }
        *(float4*)&out[rowBase + (size_t)oc * HW + pq * 4] = fv;
    }
}

// ---------------- center frame passthrough ----------------
__global__ void copy_center_k(const float* __restrict__ x, float* __restrict__ out) {
    int idx = blockIdx.x * 256 + threadIdx.x;  // < 524288 float4s
    int b = idx >> 18;
    int rem = idx & 262143;
    size_t o = (((size_t)(b * TT + TCF) * CC * HW) >> 2) + rem;
    ((float4*)out)[o] = ((const float4*)x)[o];
}

extern "C" void kernel_launch(void* const* d_in, const int* in_sizes, int n_in,
                              void* d_out, int out_size, void* d_ws, size_t ws_size,
                              hipStream_t stream) {
    const float* x = (const float*)d_in[0];
    const float* w_off1 = (const float*)d_in[1];
    const float* b_off1 = (const float*)d_in[2];
    const float* w_off2 = (const float*)d_in[3];
    const float* b_off2 = (const float*)d_in[4];
    const float* w_align1 = (const float*)d_in[5];
    const float* w_alignf = (const float*)d_in[6];
    float* out = (float*)d_out;
    float* ws = (float*)d_ws;

    float* off2 = ws;                        // 4,718,592 floats (NCHW fp32)
    float* off2u = ws + 4718592;             // 18,874,368
    float* off1 = ws + 23592960;             // 18,874,368
    short* z1T = (short*)(ws + 42467328);    // 8,921,088 shorts
    short* xT = (short*)(ws + 46927872);     // 2,230,272 shorts
    short* x2T = (short*)(ws + 48043008);    // 2,787,840 shorts
    short* wsD1 = (short*)(ws + 49436928);   // 36,864 shorts
    short* wsDf = (short*)(ws + 49455360);   // 36,864 shorts
    short* w2s = (short*)(ws + 49473792);    // 184,320 shorts
    short* w1s = (short*)(ws + 49565952);    // 512,000 shorts

    // zero the padded NHWC plane buffers (z1T, xT, x2T are contiguous)
    hipMemsetAsync((void*)z1T, 0, 27878400, stream);

    wswzD_k<<<144, 256, 0, stream>>>(w_align1, wsD1);
    wswzD_k<<<144, 256, 0, stream>>>(w_alignf, wsDf);
    wswz_k<9><<<720, 256, 0, stream>>>(w_off2, w2s);
    wswz_k<25><<<2000, 256, 0, stream>>>(w_off1, w1s);

    avgpool_k<<<dim3(64, 4, 10), 256, 0, stream>>>(x, x2T);
    xtrans_k<<<dim3(128, 4, 2), 256, 0, stream>>>(x, xT);

    convmf_k<0><<<dim3(16, 1, 8), 512, 0, stream>>>(x2T, x2T, w2s, b_off2,
                                                    nullptr, off2);
    upsample_k<<<73728, 256, 0, stream>>>(off2, off2u);
    dconv_k<<<dim3(1024, 8), 256, 0, stream>>>(x, off2u, wsD1, nullptr, z1T, 0);
    convmf_k<1><<<dim3(64, 1, 8), 512, 0, stream>>>(z1T, xT, w1s, b_off1,
                                                    off2u, off1);
    dconv_k<<<dim3(1024, 8), 256, 0, stream>>>(x, off1, wsDf, out, nullptr, 1);
    copy_center_k<<<2048, 256, 0, stream>>>(x, out);
}

// Round 7
// 748.069 us; speedup vs baseline: 2.2929x; 2.2929x over previous
//
#include <hip/hip_runtime.h>
#include <cstdint>

// Problem constants
#define BB 2
#define TT 5
#define CC 64
#define HH 128
#define WW 128
#define GG 8
#define KKD 9
#define OFFC 144
#define H2 64
#define W2 64
#define TCF 2
#define HW (HH*WW)
#define HW2 (H2*W2)
#define PLANE1 278784  // 132*132*16 shorts (full-res padded NHWC chunk plane)
#define PLANE0 69696   // 66*66*16 shorts (half-res padded NHWC chunk plane)

typedef __attribute__((ext_vector_type(4))) short short4v;
typedef __attribute__((ext_vector_type(8))) short short8;
typedef __attribute__((ext_vector_type(16))) float floatx16;

static __device__ __forceinline__ unsigned short f2bf(float f) {
    unsigned int u = __float_as_uint(f);
    unsigned int r = (u + 0x7fffu + ((u >> 16) & 1u)) >> 16;
    return (unsigned short)r;
}

typedef __attribute__((address_space(1))) const unsigned int g_u32;
typedef __attribute__((address_space(3))) unsigned int l_u32;
static __device__ __forceinline__ void async16(const short* g, short* l) {
    __builtin_amdgcn_global_load_lds((g_u32*)g, (l_u32*)l, 16, 0, 0);
}

// ---------------- dconv weight swizzle into MFMA B-fragment order (bf16) -------------
// layout: [chunk(36)][tile(2)][lane(64)][j(8)]
__global__ void wswzD_k(const float* __restrict__ w, short* __restrict__ ws) {
    int idx = blockIdx.x * 256 + threadIdx.x;
    if (idx >= 36864) return;
    int j = idx & 7;
    int lane = (idx >> 3) & 63;
    int tile = (idx >> 9) & 1;
    int chunk = idx >> 10;
    int ck = chunk * 16 + (lane >> 5) * 8 + j;
    int oc = tile * 32 + (lane & 31);
    int cin = ck / 9;
    int kt = ck - cin * 9;
    ws[idx] = (short)f2bf(w[((size_t)oc * 64 + cin) * 9 + kt]);
}

// ---------------- conv weight swizzle into MFMA fragment order (bf16) ----------------
// layout: [chunk(8)][tap(TAPS)][ocF(5)][lane(64)][j(8)]
template <int TAPS>
__global__ void wswz_k(const float* __restrict__ w, short* __restrict__ ws) {
    int idx = blockIdx.x * 256 + threadIdx.x;
    if (idx >= 8 * TAPS * 5 * 512) return;
    int jj = idx & 7;
    int lane = (idx >> 3) & 63;
    int rest = idx >> 9;
    int ocF = rest % 5;
    int ct = rest / 5;
    int tap = ct % TAPS;
    int chunk = ct / TAPS;
    int oc = ocF * 32 + (lane & 31);
    int cin = chunk * 16 + (lane >> 5) * 8 + jj;
    float v = 0.f;
    if (oc < OFFC) v = w[((size_t)oc * 128 + cin) * TAPS + tap];
    ws[idx] = (short)f2bf(v);
}

// ---------------- 2x2 average pool -> padded NHWC-bf16 chunk planes ----------------
__global__ void avgpool_k(const float* __restrict__ x, short* __restrict__ x2T) {
    __shared__ float sL[64 * 17];
    const int h2 = blockIdx.x;
    const int chunk = blockIdx.y;
    const int img = blockIdx.z;
    const int tid = threadIdx.x;
    const float* base = x + ((size_t)img * 64 + chunk * 16) * HW + (size_t)(2 * h2) * WW;
#pragma unroll
    for (int it = 0; it < 4; ++it) {
        int e = it * 256 + tid;
        int cin = e >> 6, w2 = e & 63;
        const float* sp = base + (size_t)cin * HW + 2 * w2;
        sL[w2 * 17 + cin] = 0.25f * (sp[0] + sp[1] + sp[WW] + sp[WW + 1]);
    }
    __syncthreads();
    int w2 = tid >> 2, cg = tid & 3;
    short4v sv;
#pragma unroll
    for (int q = 0; q < 4; ++q) sv[q] = (short)f2bf(sL[w2 * 17 + cg * 4 + q]);
    *(short4v*)&x2T[((size_t)img * 4 + chunk) * PLANE0 +
                    ((size_t)(h2 + 1) * 66 + (w2 + 1)) * 16 + cg * 4] = sv;
}

// ---------------- center-frame transpose -> padded NHWC-bf16 chunk planes ------------
__global__ void xtrans_k(const float* __restrict__ x, short* __restrict__ xT) {
    __shared__ float sL[128 * 17];
    const int row = blockIdx.x;
    const int chunk = blockIdx.y;
    const int b = blockIdx.z;
    const int tid = threadIdx.x;
    const float* base = x + ((size_t)(b * 5 + TCF) * 64 + chunk * 16) * HW + (size_t)row * WW;
#pragma unroll
    for (int it = 0; it < 8; ++it) {
        int e = it * 256 + tid;
        int cin = e >> 7, col = e & 127;
        sL[col * 17 + cin] = base[(size_t)cin * HW + col];
    }
    __syncthreads();
    int col = tid >> 1, half = tid & 1;
    short8 sv;
#pragma unroll
    for (int q = 0; q < 8; ++q) sv[q] = (short)f2bf(sL[col * 17 + half * 8 + q]);
    *(short8*)&xT[((size_t)b * 4 + chunk) * PLANE1 +
                  ((size_t)(row + 2) * 132 + (col + 2)) * 16 + half * 8] = sv;
}

// ---------------- MFMA conv from NHWC-bf16 planes, Cout=144 (padded 160) -------------
template <int MODE>
__global__ __launch_bounds__(512) void convmf_k(
    const short* __restrict__ srcAT, const short* __restrict__ srcBT,
    const short* __restrict__ wswz, const float* __restrict__ bias,
    const float* __restrict__ addend, float* __restrict__ out) {
    constexpr int KS = MODE ? 5 : 3;
    constexpr int IM = MODE ? 128 : 64;
    constexpr int PD = IM + KS - 1;
    constexpr int TAPS = KS * KS;
    constexpr int OROWS = MODE ? 2 : 4;
    constexpr int SROWS = OROWS + KS - 1;
    constexpr int PLANE = PD * PD * 16;
    constexpr int SLAB16 = SROWS * PD * 2;

    __shared__ __align__(16) short stg[2][SROWS * PD * 16];

    const int bj = blockIdx.z;
    const int b = bj >> 2;
    const int j = bj & 3;
    const int i = j + (j >= 2 ? 1 : 0);
    const int y0 = blockIdx.x * OROWS;
    const int tid = threadIdx.x;
    const int wave = tid >> 6;
    const int lane = tid & 63;
    const int l31 = lane & 31;
    const int quad = lane >> 5;
    const int wr = MODE ? (wave >> 2) : (wave >> 1);
    const int wc0 = MODE ? ((wave & 3) * 32) : ((wave & 1) * 32);

    const short* srcA;
    const short* srcB;
    if (MODE == 0) {
        srcA = srcAT + (size_t)((b * 5 + i) * 4) * PLANE;
        srcB = srcAT + (size_t)((b * 5 + TCF) * 4) * PLANE;
    } else {
        srcA = srcAT + (size_t)(bj * 4) * PLANE;
        srcB = srcBT + (size_t)(b * 4) * PLANE;
    }

    floatx16 acc[5];
#pragma unroll
    for (int o = 0; o < 5; ++o)
#pragma unroll
        for (int g = 0; g < 16; ++g) acc[o][g] = 0.f;

    auto stage = [&](int c, int sIdx) {
        const short* plane = (c < 4) ? (srcA + (size_t)c * PLANE)
                                     : (srcB + (size_t)(c - 4) * PLANE);
        const short* srcRow = plane + (size_t)y0 * (PD * 16);
        short* dst = stg[sIdx];
        for (int base = wave * 64; base < SLAB16; base += 512) {
            int b2 = min(base, SLAB16 - 64);
            async16(srcRow + (size_t)(b2 + lane) * 8, dst + (size_t)b2 * 8);
        }
    };

    stage(0, 0);
    for (int c = 0; c < 8; ++c) {
        __syncthreads();
        if (c < 7) stage(c + 1, (c + 1) & 1);
        const short* sbuf = stg[c & 1];
        const short* wpc = wswz + (size_t)c * TAPS * 2560 + lane * 8;
#pragma unroll 5
        for (int tap = 0; tap < TAPS; ++tap) {
            const int ky = tap / KS, kx = tap - ky * KS;
            short8 wf[5];
            const short* wp = wpc + (size_t)tap * 2560;
#pragma unroll
            for (int o = 0; o < 5; ++o) wf[o] = *(const short8*)(wp + o * 512);
            short8 pf = *(const short8*)(sbuf +
                ((size_t)(wr + ky) * PD + (wc0 + kx + l31)) * 16 + quad * 8);
#pragma unroll
            for (int o = 0; o < 5; ++o)
                acc[o] = __builtin_amdgcn_mfma_f32_32x32x16_bf16(wf[o], pf, acc[o], 0, 0, 0);
        }
    }

    const size_t imgBase = (size_t)bj * OFFC * (IM * IM);
    const size_t rowAddr = imgBase + (size_t)(y0 + wr) * IM + wc0 + l31;
#pragma unroll
    for (int o = 0; o < 5; ++o) {
        const int rmax = (o == 4) ? 8 : 16;
#pragma unroll
        for (int r = 0; r < 16; ++r) {
            if (r >= rmax) break;
            int oc = o * 32 + (r & 3) + 8 * (r >> 2) + 4 * quad;
            float v = acc[o][r] + bias[oc];
            size_t a = rowAddr + (size_t)oc * (IM * IM);
            if (MODE == 1) v += addend[a];
            out[a] = v;
        }
    }
}

// ---------------- bilinear 2x upsample * 2.0 ----------------
__global__ void upsample_k(const float* __restrict__ off2, float* __restrict__ off2u) {
    int idx = blockIdx.x * 256 + threadIdx.x;  // < 18874368
    int ox = idx & 127;
    int oy = (idx >> 7) & 127;
    int p = idx >> 14;
    const float* sp = off2 + (size_t)p * HW2;
    float sy = 0.5f * oy - 0.25f;
    float sx = 0.5f * ox - 0.25f;
    float y0f = floorf(sy), x0f = floorf(sx);
    int y0 = (int)y0f, x0 = (int)x0f;
    float fy = sy - y0f, fx = sx - x0f;
    int y0c = max(y0, 0), y1c = min(y0 + 1, 63);
    int x0c = max(x0, 0), x1c = min(x0 + 1, 63);
    float v00 = sp[y0c * 64 + x0c], v01 = sp[y0c * 64 + x1c];
    float v10 = sp[y1c * 64 + x0c], v11 = sp[y1c * 64 + x1c];
    float v = v00 * (1.f - fy) * (1.f - fx) + v01 * (1.f - fy) * fx +
              v10 * fy * (1.f - fx) + v11 * fy * fx;
    off2u[idx] = 2.0f * v;
}

// ---------------- deformable conv (3x3, G=8 offset groups), MFMA phase B -------------
// block = 256 thr (4 waves) per 32-px row segment. XCD-pinned: bj = blockIdx.x (%8
// round-robin over XCDs) so each image's 4MB gather footprint stays in one L2.
#define SROW 584
__global__ __launch_bounds__(256, 4) void dconv_k(
    const float* __restrict__ x,    // (B,T,C,H,W)
    const float* __restrict__ off,  // (BJ,144,H,W)
    const short* __restrict__ wsw,  // swizzled B-frags [chunk36][tile2][lane64][8]
    float* __restrict__ out, short* __restrict__ z1T, int outMode) {
    const int bj = blockIdx.x;   // image -> XCD (round-robin by linear block ID)
    const int b = bj >> 2;
    const int j = bj & 3;
    const int i = j + (j >= 2 ? 1 : 0);
    const int seg = blockIdx.y;  // 0..511
    const int y = seg >> 2;
    const int x0 = (seg & 3) << 5;
    const int tid = threadIdx.x;

    __shared__ short sS[32 * SROW];  // 37376 B; reused as float Pbuf[4][32][33]
    float* Pbuf = (float*)sS;

    const float* xin = x + (size_t)(b * TT + i) * CC * HW;
    const float* offp = off + (size_t)bj * OFFC * HW + y * WW + x0;

    // ---- phase A: bilinear sampling into LDS ----
    {
        const int g = tid >> 5;   // 0..7 offset group
        const int px = tid & 31;
        short* srow = sS + px * SROW + g * 72;
#pragma unroll
        for (int k = 0; k < 9; ++k) {
            float dy = offp[(size_t)((g * 9 + k) * 2) * HW + px];
            float dx = offp[(size_t)((g * 9 + k) * 2 + 1) * HW + px];
            const int kyy = k / 3 - 1;
            const int kxx = k % 3 - 1;
            float sy = (float)(y + kyy) + dy;
            float sx = (float)(x0 + px + kxx) + dx;
            float y0f = floorf(sy), x0f = floorf(sx);
            int iy = (int)y0f, ix = (int)x0f;
            float wy = sy - y0f, wx = sx - x0f;
            bool yv0 = (iy >= 0) & (iy < HH);
            bool yv1 = (iy + 1 >= 0) & (iy + 1 < HH);
            bool xv0 = (ix >= 0) & (ix < WW);
            bool xv1 = (ix + 1 >= 0) & (ix + 1 < WW);
            float w00 = (yv0 && xv0) ? (1.f - wy) * (1.f - wx) : 0.f;
            float w01 = (yv0 && xv1) ? (1.f - wy) * wx : 0.f;
            float w10 = (yv1 && xv0) ? wy * (1.f - wx) : 0.f;
            float w11 = (yv1 && xv1) ? wy * wx : 0.f;
            int iy0 = min(max(iy, 0), HH - 1);
            int iy1 = min(max(iy + 1, 0), HH - 1);
            int ix0 = min(max(ix, 0), WW - 1);
            int ix1 = min(max(ix + 1, 0), WW - 1);
            int o00 = iy0 * WW + ix0, o01 = iy0 * WW + ix1;
            int o10 = iy1 * WW + ix0, o11 = iy1 * WW + ix1;
            const float* xp = xin + (size_t)(g * 8) * HW;
#pragma unroll 4
            for (int c = 0; c < 8; ++c) {
                float v = xp[o00] * w00 + xp[o01] * w01 + xp[o10] * w10 + xp[o11] * w11;
                srow[c * 9 + k] = (short)f2bf(v);
                xp += HW;
            }
        }
    }
    __syncthreads();

    // ---- phase B: C[px 32][oc 64] = S * W, K=576, MFMA 32x32x16 ----
    const int wv = tid >> 6;      // wave 0..3
    const int lane = tid & 63;
    const int tile = wv >> 1;     // oc tile
    const int kw = wv & 1;        // K half
    floatx16 acc;
#pragma unroll
    for (int g = 0; g < 16; ++g) acc[g] = 0.f;

    const short* aBase = sS + (lane & 31) * SROW + (lane >> 5) * 8;
    const short* bBase = wsw + ((size_t)tile * 64 + lane) * 8;
    for (int chunk = kw * 18; chunk < kw * 18 + 18; ++chunk) {
        short8 af = *(const short8*)(aBase + chunk * 16);
        short8 bf = *(const short8*)(bBase + (size_t)chunk * 1024);
        acc = __builtin_amdgcn_mfma_f32_32x32x16_bf16(af, bf, acc, 0, 0, 0);
    }

    __syncthreads();  // all waves done reading sS; alias as Pbuf
    {
        const int n = lane & 31;
#pragma unroll
        for (int g = 0; g < 16; ++g) {
            int m = (g & 3) + 8 * (g >> 2) + 4 * (lane >> 5);
            Pbuf[wv * 1056 + m * 33 + n] = acc[g];
        }
    }
    __syncthreads();

    // ---- epilogue: reduce K-halves, store ----
    if (outMode == 0) {
        const int chunk = tid >> 6;
        const int px = (tid >> 1) & 31;
        const int half = tid & 1;
        const int t2 = chunk >> 1;
        const int n0 = (chunk & 1) * 16 + half * 8;
        short8 sv;
#pragma unroll
        for (int q = 0; q < 8; ++q) {
            float v = Pbuf[(t2 * 2) * 1056 + px * 33 + n0 + q] +
                      Pbuf[(t2 * 2 + 1) * 1056 + px * 33 + n0 + q];
            sv[q] = (short)f2bf(v);
        }
        *(short8*)&z1T[((size_t)bj * 4 + chunk) * PLANE1 +
                       ((size_t)(y + 2) * 132 + (x0 + 2 + px)) * 16 + half * 8] = sv;
    } else {
        const size_t planeBase = (size_t)(b * TT + i) * CC * HW;
        const size_t rowBase = planeBase + (size_t)y * WW + x0;
#pragma unroll
        for (int rep = 0; rep < 8; ++rep) {
            int elem = rep * 256 + tid;
            int oc = elem >> 5;
            int px = elem & 31;
            int t = oc >> 5;
            int n = oc & 31;
            float v = Pbuf[(t * 2) * 1056 + px * 33 + n] +
                      Pbuf[(t * 2 + 1) * 1056 + px * 33 + n];
            out[rowBase + (size_t)oc * HW + px] = v;
        }
    }
}

// ---------------- center frame passthrough ----------------
__global__ void copy_center_k(const float* __restrict__ x, float* __restrict__ out) {
    int idx = blockIdx.x * 256 + threadIdx.x;  // < 524288 float4s
    int b = idx >> 18;
    int rem = idx & 262143;
    size_t o = (((size_t)(b * TT + TCF) * CC * HW) >> 2) + rem;
    ((float4*)out)[o] = ((const float4*)x)[o];
}

extern "C" void kernel_launch(void* const* d_in, const int* in_sizes, int n_in,
                              void* d_out, int out_size, void* d_ws, size_t ws_size,
                              hipStream_t stream) {
    const float* x = (const float*)d_in[0];
    const float* w_off1 = (const float*)d_in[1];
    const float* b_off1 = (const float*)d_in[2];
    const float* w_off2 = (const float*)d_in[3];
    const float* b_off2 = (const float*)d_in[4];
    const float* w_align1 = (const float*)d_in[5];
    const float* w_alignf = (const float*)d_in[6];
    float* out = (float*)d_out;
    float* ws = (float*)d_ws;

    float* off2 = ws;                        // 4,718,592 floats (NCHW fp32)
    float* off2u = ws + 4718592;             // 18,874,368
    float* off1 = ws + 23592960;             // 18,874,368
    short* z1T = (short*)(ws + 42467328);    // 8,921,088 shorts
    short* xT = (short*)(ws + 46927872);     // 2,230,272 shorts
    short* x2T = (short*)(ws + 48043008);    // 2,787,840 shorts
    short* wsD1 = (short*)(ws + 49436928);   // 36,864 shorts
    short* wsDf = (short*)(ws + 49455360);   // 36,864 shorts
    short* w2s = (short*)(ws + 49473792);    // 184,320 shorts
    short* w1s = (short*)(ws + 49565952);    // 512,000 shorts

    // zero the padded NHWC plane buffers (z1T, xT, x2T are contiguous)
    hipMemsetAsync((void*)z1T, 0, 27878400, stream);

    wswzD_k<<<144, 256, 0, stream>>>(w_align1, wsD1);
    wswzD_k<<<144, 256, 0, stream>>>(w_alignf, wsDf);
    wswz_k<9><<<720, 256, 0, stream>>>(w_off2, w2s);
    wswz_k<25><<<2000, 256, 0, stream>>>(w_off1, w1s);

    avgpool_k<<<dim3(64, 4, 10), 256, 0, stream>>>(x, x2T);
    xtrans_k<<<dim3(128, 4, 2), 256, 0, stream>>>(x, xT);

    convmf_k<0><<<dim3(16, 1, 8), 512, 0, stream>>>(x2T, x2T, w2s, b_off2,
                                                    nullptr, off2);
    upsample_k<<<73728, 256, 0, stream>>>(off2, off2u);
    dconv_k<<<dim3(8, 512), 256, 0, stream>>>(x, off2u, wsD1, nullptr, z1T, 0);
    convmf_k<1><<<dim3(64, 1, 8), 512, 0, stream>>>(z1T, xT, w1s, b_off1,
                                                    off2u, off1);
    dconv_k<<<dim3(8, 512), 256, 0, stream>>>(x, off1, wsDf, out, nullptr, 1);
    copy_center_k<<<2048, 256, 0, stream>>>(x, out);
}